// Round 2
// baseline (2180.458 us; speedup 1.0000x reference)
//
#include <hip/hip_runtime.h>
#include <hip/hip_bf16.h>

// BATPoseDecoder on MI355X (gfx950). B=4,N=256,M=256,D=524, fp32 in/out.
// R2: (1) fold ow1 into GEMM1 (matched@ow1 = sum_m p_m * (L[m,:]@ow1)) -> no L
// re-read, no 524-step overlap loop; (2) 512-thr blocks (16 waves/CU);
// (3) 2 M-tiles per K-loop pass (half the barriers, 2x W-frag reuse).

#define D_ 524
#define CW_OFF 64
#define OV_OFF 262208  // 64 + 4*256*256

// ws byte offsets
#define W1H_OFF 0        // 17kk x 24ct x 64 lanes x 8 shorts = 417792 B
#define W1L_OFF 417792   // 17kk x 16ct x 64 x 8 = 278528 B
#define W2H_OFF 696320   // 8kk x 8ct x 64 x 8 = 65536 B
#define W2L_OFF 761856   // 65536 B
#define TGTM_OFF 827392  // 1024*3*4 = 12288 B

typedef __attribute__((ext_vector_type(8))) short short8;
typedef __attribute__((ext_vector_type(4))) float floatx4;

__device__ __forceinline__ short f2bf(float v) {
  unsigned u = __builtin_bit_cast(unsigned, v);
  unsigned r = (u + 0x7FFFu + ((u >> 16) & 1u)) >> 16;  // RNE
  return (short)(unsigned short)r;
}
__device__ __forceinline__ float bf2f(short s) {
  unsigned u = ((unsigned)(unsigned short)s) << 16;
  return __builtin_bit_cast(float, u);
}

// ---- prep: W1'=[cw1|ow1] K-padded to 544, hi(+lo for cw1 cols) bf16 frags;
// W2 hi/lo frags. Frag order: (kk*CT + ct)*64 + lane, 8 shorts each.
__global__ void prep_kernel(const float* __restrict__ cw1, const float* __restrict__ ow1,
                            const float* __restrict__ cw2,
                            short* __restrict__ w1h, short* __restrict__ w1l,
                            short* __restrict__ w2h, short* __restrict__ w2l) {
  int t = blockIdx.x * 256 + threadIdx.x;
  if (t < 26112) {  // 17*24*64
    int lane = t & 63, ct = (t >> 6) % 24, kk = t / 1536;
    int cl = lane & 15, kb = kk * 32 + ((lane >> 4) << 3);
    bool isW1 = ct < 16;
    int lo_base = ((kk * 16 + ct) * 64 + lane) * 8;
#pragma unroll
    for (int i = 0; i < 8; ++i) {
      int k = kb + i;
      float v = 0.f;
      if (k < D_) v = isW1 ? cw1[k * 256 + ct * 16 + cl] : ow1[k * 128 + (ct - 16) * 16 + cl];
      short h = f2bf(v);
      w1h[t * 8 + i] = h;
      if (isW1) w1l[lo_base + i] = f2bf(v - bf2f(h));
    }
  } else if (t < 30208) {  // 8*8*64
    int u = t - 26112;
    int lane = u & 63, ct = (u >> 6) & 7, kk = u >> 9;
    int col = ct * 16 + (lane & 15), kb = kk * 32 + ((lane >> 4) << 3);
#pragma unroll
    for (int i = 0; i < 8; ++i) {
      float v = cw2[(kb + i) * 128 + col];
      short h = f2bf(v);
      w2h[u * 8 + i] = h;
      w2l[u * 8 + i] = f2bf(v - bf2f(h));
    }
  }
}

// ---- main: one 512-thr block per (b,n). Wave w owns W1-cts {2w,2w+1}, g-ct {16+w},
// W2-ct {w}. 2 M-tiles (64 rows each) share one K-loop pass.
__global__ __launch_bounds__(512, 2) void main_kernel(
    const float* __restrict__ L, const float* __restrict__ tgt,
    const float* __restrict__ cb1, const float* __restrict__ cb2,
    const float* __restrict__ cw3, const float* __restrict__ cb3,
    const float* __restrict__ ob1, const float* __restrict__ ow2,
    const float* __restrict__ ob2,
    const short8* __restrict__ w1h, const short8* __restrict__ w1l,
    const short8* __restrict__ w2h, const short8* __restrict__ w2l,
    float* __restrict__ out, float* __restrict__ tgtm) {
  int bn = blockIdx.x, b = bn >> 8, t = threadIdx.x;
  int w = t >> 6, lane = t & 63, l15 = lane & 15, q = lane >> 4;

  __shared__ __attribute__((aligned(16))) short Ah[2][2][64 * 40];  // 20480 B (stride 40 -> 2-way banks)
  __shared__ __attribute__((aligned(16))) short h1s[64 * 272];      // 34816 B (stride 272 -> 4-way)
  __shared__ float p_all[256];
  __shared__ float redw[512];
  __shared__ float sS;

  const float* Lbn = L + (size_t)bn * (256 * D_);
  float ua = 0.f;  // overlap pre-act accumulator for col j = w*16+l15 (dup over q)

  int mt_s = t >> 8, srow = (t >> 2) & 63, sko = (t & 3) * 8;

#pragma unroll 1
  for (int mp = 0; mp < 2; ++mp) {
    const float* Lr0 = Lbn + (size_t)(mp * 128 + mt_s * 64 + srow) * D_;

    floatx4 acc[2][4][2];  // [mt][rt][ctW]
    floatx4 accg[2][4];    // [mt][rt]
#pragma unroll
    for (int mt = 0; mt < 2; ++mt)
#pragma unroll
      for (int r = 0; r < 4; ++r) {
        acc[mt][r][0] = (floatx4)(0.f);
        acc[mt][r][1] = (floatx4)(0.f);
        accg[mt][r] = (floatx4)(0.f);
      }

    {  // stage kstep 0
      floatx4 v0 = *(const floatx4*)(Lr0 + sko);
      floatx4 v1 = *(const floatx4*)(Lr0 + sko + 4);
      short8 sv;
#pragma unroll
      for (int j = 0; j < 4; ++j) { sv[j] = f2bf(v0[j]); sv[4 + j] = f2bf(v1[j]); }
      *(short8*)&Ah[0][mt_s][srow * 40 + sko] = sv;
    }
    __syncthreads();

#pragma unroll 1
    for (int kk = 0; kk < 17; ++kk) {
      int cb = kk & 1;
      // global prefetch of next slab first (longest latency)
      floatx4 nv0, nv1;
      if (kk < 15) {
        nv0 = *(const floatx4*)(Lr0 + (kk + 1) * 32 + sko);
        nv1 = *(const floatx4*)(Lr0 + (kk + 1) * 32 + sko + 4);
      } else if (kk == 15) {
#pragma unroll
        for (int j = 0; j < 4; ++j) {
          int k0 = 512 + sko + j, k1 = 516 + sko + j;
          nv0[j] = (k0 < D_) ? Lr0[k0] : 0.f;
          nv1[j] = (k1 < D_) ? Lr0[k1] : 0.f;
        }
      }
      // W fragments (L2-resident)
      short8 bh0 = w1h[(kk * 24 + 2 * w) * 64 + lane];
      short8 bh1 = w1h[(kk * 24 + 2 * w + 1) * 64 + lane];
      short8 gh = w1h[(kk * 24 + 16 + w) * 64 + lane];
      short8 bl0 = w1l[(kk * 16 + 2 * w) * 64 + lane];
      short8 bl1 = w1l[(kk * 16 + 2 * w + 1) * 64 + lane];
      // A fragments from LDS
      short8 af[2][4];
#pragma unroll
      for (int mt = 0; mt < 2; ++mt)
#pragma unroll
        for (int r = 0; r < 4; ++r)
          af[mt][r] = *(const short8*)&Ah[cb][mt][(r * 16 + l15) * 40 + q * 8];
#pragma unroll
      for (int mt = 0; mt < 2; ++mt)
#pragma unroll
        for (int r = 0; r < 4; ++r) {
          acc[mt][r][0] = __builtin_amdgcn_mfma_f32_16x16x32_bf16(af[mt][r], bh0, acc[mt][r][0], 0, 0, 0);
          acc[mt][r][0] = __builtin_amdgcn_mfma_f32_16x16x32_bf16(af[mt][r], bl0, acc[mt][r][0], 0, 0, 0);
          acc[mt][r][1] = __builtin_amdgcn_mfma_f32_16x16x32_bf16(af[mt][r], bh1, acc[mt][r][1], 0, 0, 0);
          acc[mt][r][1] = __builtin_amdgcn_mfma_f32_16x16x32_bf16(af[mt][r], bl1, acc[mt][r][1], 0, 0, 0);
          accg[mt][r] = __builtin_amdgcn_mfma_f32_16x16x32_bf16(af[mt][r], gh, accg[mt][r], 0, 0, 0);
        }
      if (kk < 16) {
        short8 sv;
#pragma unroll
        for (int j = 0; j < 4; ++j) { sv[j] = f2bf(nv0[j]); sv[4 + j] = f2bf(nv1[j]); }
        *(short8*)&Ah[cb ^ 1][mt_s][srow * 40 + sko] = sv;
      }
      __syncthreads();
    }

    // per-M-tile: epilogue -> GEMM2 -> scores -> p -> g-reduce
#pragma unroll 1
    for (int mt = 0; mt < 2; ++mt) {
      int m0 = mp * 128 + mt * 64;
#pragma unroll
      for (int c = 0; c < 2; ++c) {
        int col = (2 * w + c) * 16 + l15;
        float b1 = cb1[col];
#pragma unroll
        for (int r = 0; r < 4; ++r)
#pragma unroll
          for (int i = 0; i < 4; ++i)
            h1s[(r * 16 + q * 4 + i) * 272 + col] = f2bf(fmaxf(acc[mt][r][c][i] + b1, 0.f));
      }
      __syncthreads();

      floatx4 ac2[4];
#pragma unroll
      for (int r = 0; r < 4; ++r) ac2[r] = (floatx4)(0.f);
#pragma unroll 1
      for (int kk = 0; kk < 8; ++kk) {
        short8 b2h_ = w2h[(kk * 8 + w) * 64 + lane];
        short8 b2l_ = w2l[(kk * 8 + w) * 64 + lane];
        short8 a2[4];
#pragma unroll
        for (int r = 0; r < 4; ++r)
          a2[r] = *(const short8*)&h1s[(r * 16 + l15) * 272 + kk * 32 + q * 8];
#pragma unroll
        for (int r = 0; r < 4; ++r) {
          ac2[r] = __builtin_amdgcn_mfma_f32_16x16x32_bf16(a2[r], b2h_, ac2[r], 0, 0, 0);
          ac2[r] = __builtin_amdgcn_mfma_f32_16x16x32_bf16(a2[r], b2l_, ac2[r], 0, 0, 0);
        }
      }
      // scores: sum over this wave's 16 h2-cols
      int col2 = w * 16 + l15;
      float b2 = cb2[col2], w3 = cw3[col2];
      float pr[4][4];
#pragma unroll
      for (int r = 0; r < 4; ++r)
#pragma unroll
        for (int i = 0; i < 4; ++i)
          pr[r][i] = fmaxf(ac2[r][i] + b2, 0.f) * w3;
#pragma unroll
      for (int m = 1; m <= 8; m <<= 1)
#pragma unroll
        for (int r = 0; r < 4; ++r)
#pragma unroll
          for (int i = 0; i < 4; ++i) pr[r][i] += __shfl_xor(pr[r][i], m, 64);
      if (l15 == 0) {
#pragma unroll
        for (int r = 0; r < 4; ++r)
#pragma unroll
          for (int i = 0; i < 4; ++i) redw[w * 64 + r * 16 + q * 4 + i] = pr[r][i];
      }
      __syncthreads();
      if (t < 64) {
        float s = cb3[0];
#pragma unroll
        for (int ww = 0; ww < 8; ++ww) s += redw[ww * 64 + t];
        p_all[m0 + t] = expf(s);  // raw exp == softmax numerator (scores O(1))
      }
      __syncthreads();
      // weighted-g reduction: ua[col] += sum_m p_m * g[m,col]
      float gv = 0.f;
#pragma unroll
      for (int r = 0; r < 4; ++r)
#pragma unroll
        for (int i = 0; i < 4; ++i)
          gv += p_all[m0 + r * 16 + q * 4 + i] * accg[mt][r][i];
      gv += __shfl_xor(gv, 16, 64);
      gv += __shfl_xor(gv, 32, 64);
      ua += gv;
    }
  }

  // softmax denominator
  if (t < 64) redw[t] = p_all[t] + p_all[t + 64] + p_all[t + 128] + p_all[t + 192];
  __syncthreads();
  if (t == 0) {
    float s = 0.f;
    for (int i = 0; i < 64; ++i) s += redw[i];
    sS = 1.f / s;
  }
  __syncthreads();
  float invS = sS;
  if (t < 256) out[CW_OFF + bn * 256 + t] = p_all[t] * invS;

  // overlap: u = ua*invS + ob1 ; o = sum relu(u)*ow2 + ob2 -> sigmoid
  {
    float u = ua * invS + ob1[w * 16 + l15];
    float r = fmaxf(u, 0.f) * ow2[w * 16 + l15];
    if (q != 0) r = 0.f;
#pragma unroll
    for (int m = 1; m <= 32; m <<= 1) r += __shfl_xor(r, m, 64);
    if (lane == 0) redw[256 + w] = r;
  }
  // tgt_matched partials
  if (t < 96) {
    int c = t % 3, g = t / 3;
    float s = 0.f;
#pragma unroll
    for (int m = 0; m < 8; ++m) s += p_all[g * 8 + m] * tgt[((b * 256) + g * 8 + m) * 3 + c];
    redw[320 + t] = s;
  }
  __syncthreads();
  if (t == 0) {
    float o = ob2[0];
    for (int ww = 0; ww < 8; ++ww) o += redw[256 + ww];
    out[OV_OFF + bn] = 1.f / (1.f + expf(-o));
  }
  if (t < 3) {
    float s = 0.f;
    for (int g = 0; g < 32; ++g) s += redw[320 + g * 3 + t];
    tgtm[bn * 3 + t] = s * invS;
  }
}

// ---- finalize: per-batch Kabsch via fp64 Jacobi SVD + Shepperd quaternion
__global__ __launch_bounds__(256) void finalize_kernel(const float* __restrict__ src,
                                                       const float* __restrict__ tgtm,
                                                       float* __restrict__ out) {
  int b = blockIdx.x, t = threadIdx.x;
  __shared__ float red[256];

  auto bsum = [&](float v) -> float {
    red[t] = v;
    __syncthreads();
    for (int s = 128; s > 0; s >>= 1) {
      if (t < s) red[t] += red[t + s];
      __syncthreads();
    }
    float r = red[0];
    __syncthreads();
    return r;
  };

  float wv = out[OV_OFF + b * 256 + t];
  float Sw = bsum(wv);
  float wn = wv / fmaxf(Sw, 1e-8f);
  float sc[3], tm[3];
#pragma unroll
  for (int c = 0; c < 3; ++c) {
    sc[c] = src[(b * 256 + t) * 3 + c];
    tm[c] = tgtm[(b * 256 + t) * 3 + c];
  }
  float sb[3], tb[3];
#pragma unroll
  for (int c = 0; c < 3; ++c) sb[c] = bsum(wn * sc[c]);
#pragma unroll
  for (int c = 0; c < 3; ++c) tb[c] = bsum(wn * tm[c]);
  float Hv[9];
#pragma unroll
  for (int c = 0; c < 3; ++c)
#pragma unroll
    for (int d = 0; d < 3; ++d)
      Hv[c * 3 + d] = bsum((sc[c] - sb[c]) * wn * (tm[d] - tb[d]));

  if (t == 0) {
    double H[3][3];
    for (int i = 0; i < 3; ++i)
      for (int j = 0; j < 3; ++j) H[i][j] = (double)Hv[i * 3 + j];
    double A[3][3], V[3][3] = {{1, 0, 0}, {0, 1, 0}, {0, 0, 1}};
    for (int i = 0; i < 3; ++i)
      for (int j = 0; j < 3; ++j) {
        double s = 0;
        for (int k = 0; k < 3; ++k) s += H[k][i] * H[k][j];
        A[i][j] = s;
      }
    const int PQ[3][2] = {{0, 1}, {0, 2}, {1, 2}};
    for (int sweep = 0; sweep < 30; ++sweep)
      for (int r = 0; r < 3; ++r) {
        int p = PQ[r][0], qq = PQ[r][1];
        double apq = A[p][qq];
        if (fabs(apq) < 1e-300) continue;
        double tau = (A[qq][qq] - A[p][p]) / (2.0 * apq);
        double tt = (tau >= 0 ? 1.0 : -1.0) / (fabs(tau) + sqrt(1.0 + tau * tau));
        double cc = 1.0 / sqrt(1.0 + tt * tt), ss = tt * cc;
        for (int k = 0; k < 3; ++k) {
          double akp = A[k][p], akq = A[k][qq];
          A[k][p] = cc * akp - ss * akq;
          A[k][qq] = ss * akp + cc * akq;
        }
        for (int k = 0; k < 3; ++k) {
          double apk = A[p][k], aqk = A[qq][k];
          A[p][k] = cc * apk - ss * aqk;
          A[qq][k] = ss * apk + cc * aqk;
        }
        for (int k = 0; k < 3; ++k) {
          double vkp = V[k][p], vkq = V[k][qq];
          V[k][p] = cc * vkp - ss * vkq;
          V[k][qq] = ss * vkp + cc * vkq;
        }
      }
    int idx[3] = {0, 1, 2};
    for (int i = 0; i < 2; ++i)
      for (int j = i + 1; j < 3; ++j)
        if (A[idx[j]][idx[j]] > A[idx[i]][idx[i]]) { int tmp = idx[i]; idx[i] = idx[j]; idx[j] = tmp; }
    double v0[3], v1[3], v2[3];
    for (int k = 0; k < 3; ++k) {
      v0[k] = V[k][idx[0]];
      v1[k] = V[k][idx[1]];
      v2[k] = V[k][idx[2]];
    }
    double u0[3], u1[3], u2[3];
    for (int j = 0; j < 3; ++j) {
      u0[j] = H[j][0] * v0[0] + H[j][1] * v0[1] + H[j][2] * v0[2];
      u1[j] = H[j][0] * v1[0] + H[j][1] * v1[1] + H[j][2] * v1[2];
    }
    double n0 = sqrt(u0[0] * u0[0] + u0[1] * u0[1] + u0[2] * u0[2]);
    n0 = (n0 > 1e-300) ? n0 : 1e-300;
    for (int j = 0; j < 3; ++j) u0[j] /= n0;
    double d01 = u0[0] * u1[0] + u0[1] * u1[1] + u0[2] * u1[2];
    for (int j = 0; j < 3; ++j) u1[j] -= d01 * u0[j];
    double n1 = sqrt(u1[0] * u1[0] + u1[1] * u1[1] + u1[2] * u1[2]);
    n1 = (n1 > 1e-300) ? n1 : 1e-300;
    for (int j = 0; j < 3; ++j) u1[j] /= n1;
    u2[0] = u0[1] * u1[2] - u0[2] * u1[1];
    u2[1] = u0[2] * u1[0] - u0[0] * u1[2];
    u2[2] = u0[0] * u1[1] - u0[1] * u1[0];
    double Rr[3][3];
    for (int i = 0; i < 3; ++i)
      for (int j = 0; j < 3; ++j)
        Rr[i][j] = v0[i] * u0[j] + v1[i] * u1[j] + v2[i] * u2[j];
    double det = Rr[0][0] * (Rr[1][1] * Rr[2][2] - Rr[1][2] * Rr[2][1]) -
                 Rr[0][1] * (Rr[1][0] * Rr[2][2] - Rr[1][2] * Rr[2][0]) +
                 Rr[0][2] * (Rr[1][0] * Rr[2][1] - Rr[1][1] * Rr[2][0]);
    double sg = (det >= 0) ? 1.0 : -1.0;
    double R[3][3];
    for (int i = 0; i < 3; ++i)
      for (int j = 0; j < 3; ++j)
        R[i][j] = v0[i] * u0[j] + v1[i] * u1[j] + sg * v2[i] * u2[j];
    double trv[3];
    for (int i = 0; i < 3; ++i)
      trv[i] = (double)tb[i] - (R[i][0] * sb[0] + R[i][1] * sb[1] + R[i][2] * sb[2]);
    double qv[4];
    double tr = R[0][0] + R[1][1] + R[2][2];
    if (tr > 0) {
      double S = sqrt(fmax(tr + 1.0, 1e-10)) * 2.0;
      qv[0] = (R[2][1] - R[1][2]) / S;
      qv[1] = (R[0][2] - R[2][0]) / S;
      qv[2] = (R[1][0] - R[0][1]) / S;
      qv[3] = 0.25 * S;
    } else if (R[0][0] > R[1][1] && R[0][0] > R[2][2]) {
      double S = sqrt(fmax(1.0 + R[0][0] - R[1][1] - R[2][2], 1e-10)) * 2.0;
      qv[0] = 0.25 * S;
      qv[1] = (R[0][1] + R[1][0]) / S;
      qv[2] = (R[0][2] + R[2][0]) / S;
      qv[3] = (R[2][1] - R[1][2]) / S;
    } else if (R[1][1] > R[2][2]) {
      double S = sqrt(fmax(1.0 + R[1][1] - R[0][0] - R[2][2], 1e-10)) * 2.0;
      qv[0] = (R[0][1] + R[1][0]) / S;
      qv[1] = 0.25 * S;
      qv[2] = (R[1][2] + R[2][1]) / S;
      qv[3] = (R[0][2] - R[2][0]) / S;
    } else {
      double S = sqrt(fmax(1.0 + R[2][2] - R[0][0] - R[1][1], 1e-10)) * 2.0;
      qv[0] = (R[0][2] + R[2][0]) / S;
      qv[1] = (R[1][2] + R[2][1]) / S;
      qv[2] = 0.25 * S;
      qv[3] = (R[1][0] - R[0][1]) / S;
    }
    double qn = sqrt(qv[0] * qv[0] + qv[1] * qv[1] + qv[2] * qv[2] + qv[3] * qv[3]);
    qn = fmax(qn, 1e-12);
    for (int k = 0; k < 4; ++k) out[b * 4 + k] = (float)(qv[k] / qn);
    for (int i = 0; i < 3; ++i) out[16 + b * 3 + i] = (float)trv[i];
    for (int i = 0; i < 3; ++i)
      for (int j = 0; j < 3; ++j) out[28 + b * 9 + i * 3 + j] = (float)R[i][j];
  }
}

extern "C" void kernel_launch(void* const* d_in, const int* in_sizes, int n_in,
                              void* d_out, int out_size, void* d_ws, size_t ws_size,
                              hipStream_t stream) {
  const float* L = (const float*)d_in[0];
  const float* src = (const float*)d_in[1];
  const float* tgt = (const float*)d_in[2];
  const float* cw1 = (const float*)d_in[3];
  const float* cb1 = (const float*)d_in[4];
  const float* cw2 = (const float*)d_in[5];
  const float* cb2 = (const float*)d_in[6];
  const float* cw3 = (const float*)d_in[7];
  const float* cb3 = (const float*)d_in[8];
  const float* ow1 = (const float*)d_in[9];
  const float* ob1 = (const float*)d_in[10];
  const float* ow2 = (const float*)d_in[11];
  const float* ob2 = (const float*)d_in[12];
  float* out = (float*)d_out;

  char* ws = (char*)d_ws;
  short* w1h = (short*)(ws + W1H_OFF);
  short* w1l = (short*)(ws + W1L_OFF);
  short* w2h = (short*)(ws + W2H_OFF);
  short* w2l = (short*)(ws + W2L_OFF);
  float* tgtm = (float*)(ws + TGTM_OFF);

  hipLaunchKernelGGL(prep_kernel, dim3(118), dim3(256), 0, stream, cw1, ow1, cw2, w1h, w1l, w2h, w2l);
  hipLaunchKernelGGL(main_kernel, dim3(1024), dim3(512), 0, stream,
                     L, tgt, cb1, cb2, cw3, cb3, ob1, ow2, ob2,
                     (const short8*)w1h, (const short8*)w1l,
                     (const short8*)w2h, (const short8*)w2l, out, tgtm);
  hipLaunchKernelGGL(finalize_kernel, dim3(4), dim3(256), 0, stream, src, tgtm, out);
}